// Round 9
// baseline (3325.789 us; speedup 1.0000x reference)
//
#include <hip/hip_runtime.h>

typedef short bf16x8 __attribute__((ext_vector_type(8)));
typedef float f32x4  __attribute__((ext_vector_type(4)));
typedef unsigned long long u64;

#define MFMA16(a, b, c) __builtin_amdgcn_mfma_f32_16x16x32_bf16((a), (b), (c), 0, 0, 0)
#define AT_LD(p, o)    __hip_atomic_load((p), (o), __HIP_MEMORY_SCOPE_AGENT)
#define AT_ST(p, v, o) __hip_atomic_store((p), (v), (o), __HIP_MEMORY_SCOPE_AGENT)
#define AT_ADD(p, v, o) __hip_atomic_fetch_add((p), (v), (o), __HIP_MEMORY_SCOPE_AGENT)

#define HSLOT 67584      // h ring slot stride in bf16 elems (128KB + 4KB pad)

__device__ __forceinline__ unsigned short f2bf(float f) {
  union { float f; unsigned u; } v; v.f = f;
  unsigned u = v.u;
  u += 0x7fffu + ((u >> 16) & 1u);
  return (unsigned short)(u >> 16);
}
__device__ __forceinline__ float bf2f(unsigned short h) {
  union { unsigned u; float f; } v; v.u = ((unsigned)h) << 16;
  return v.f;
}
__device__ __forceinline__ float sigf(float x) { return 1.f / (1.f + __expf(-x)); }
__device__ __forceinline__ float tanh_(float x) {
  x = fminf(15.f, fmaxf(-15.f, x));
  float e = __expf(2.f * x);
  return (e - 1.f) / (e + 1.f);
}

// ======== flag-array barrier for k_rec (128 wgs, zero atomic serialization) ========
// bar words: flags[wg] at wg*64 (256B apart), gen at word 8192.
__device__ __forceinline__ void flagbar(unsigned* bar, int wg, unsigned target,
                                        int do_acq) {
  unsigned* gen = bar + 8192;
  __syncthreads();                       // all work + h stores drained (vmcnt)
  if (threadIdx.x == 0) {
    asm volatile("" ::: "memory");
    AT_ST(bar + wg * 64, target, __ATOMIC_RELAXED);
  }
  if (wg == 0) {
    if (threadIdx.x < 128) {
      while (AT_LD(bar + threadIdx.x * 64, __ATOMIC_RELAXED) < target)
        __builtin_amdgcn_s_sleep(1);
    }
    __syncthreads();
    if (threadIdx.x == 0) AT_ST(gen, target, __ATOMIC_RELAXED);
  } else {
    if (threadIdx.x == 0) {
      while (AT_LD(gen, __ATOMIC_RELAXED) < target) __builtin_amdgcn_s_sleep(1);
    }
  }
  if (do_acq && threadIdx.x == 0) {
    (void)AT_LD(gen, __ATOMIC_ACQUIRE);  // one L1/L2 inv per 16 steps (h-ring refresh)
    asm volatile("" ::: "memory");
  }
  __syncthreads();
}

// ---- R8 tree barriers (fused fallback path only) ----
__device__ __forceinline__ void gbar_rec(unsigned* bar, int wg, unsigned target) {
  __syncthreads();
  if (threadIdx.x == 0) {
    asm volatile("" ::: "memory");
    unsigned arr = AT_ADD(bar + (wg & 3) * 64, 1u, __ATOMIC_RELAXED);
    if (arr == target * 32u - 1u) {
      unsigned rarr = AT_ADD(bar + 256, 1u, __ATOMIC_RELAXED);
      if (rarr == target * 4u - 1u) AT_ST(bar + 320, target, __ATOMIC_RELAXED);
    }
    while (AT_LD(bar + 320, __ATOMIC_RELAXED) < target) __builtin_amdgcn_s_sleep(1);
    asm volatile("" ::: "memory");
  }
  __syncthreads();
}
__device__ __forceinline__ void gbar_gemm(unsigned* bar, unsigned target) {
  __syncthreads();
  if (threadIdx.x == 0) {
    unsigned arr = AT_ADD(bar + 384, 1u, __ATOMIC_RELEASE);
    if (arr == target * 128u - 1u) AT_ST(bar + 448, target, __ATOMIC_RELEASE);
    while (AT_LD(bar + 448, __ATOMIC_RELAXED) < target) __builtin_amdgcn_s_sleep(4);
    asm volatile("" ::: "memory");
  }
  __syncthreads();
}

// ---------------- weight conversion fp32 -> bf16 ----------------
__global__ void k_conv(const float* __restrict__ wih, const float* __restrict__ whh,
                       const float* __restrict__ wemb,
                       unsigned short* __restrict__ oih, unsigned short* __restrict__ ohh,
                       unsigned short* __restrict__ oemb) {
  const size_t NIH = (size_t)4096 * 512, NHH = (size_t)4096 * 1024;
  const size_t NE = (size_t)32000 * 512;
  size_t i0 = ((size_t)blockIdx.x * blockDim.x + threadIdx.x) * 4;
  size_t gs = (size_t)gridDim.x * blockDim.x * 4;
  for (size_t j = i0; j < NIH; j += gs) {
    float4 v = *(const float4*)(wih + j);
    uint2 pk;
    pk.x = (unsigned)f2bf(v.x) | ((unsigned)f2bf(v.y) << 16);
    pk.y = (unsigned)f2bf(v.z) | ((unsigned)f2bf(v.w) << 16);
    *(uint2*)(oih + j) = pk;
  }
  for (size_t j = i0; j < NHH; j += gs) {
    float4 v = *(const float4*)(whh + j);
    uint2 pk;
    pk.x = (unsigned)f2bf(v.x) | ((unsigned)f2bf(v.y) << 16);
    pk.y = (unsigned)f2bf(v.z) | ((unsigned)f2bf(v.w) << 16);
    *(uint2*)(ohh + j) = pk;
  }
  if (oemb)
    for (size_t j = i0; j < NE; j += gs) {
      float4 v = *(const float4*)(wemb + j);
      uint2 pk;
      pk.x = (unsigned)f2bf(v.x) | ((unsigned)f2bf(v.y) << 16);
      pk.y = (unsigned)f2bf(v.z) | ((unsigned)f2bf(v.w) << 16);
      *(uint2*)(oemb + j) = pk;
    }
}

// ---------------- lengths / selection index ----------------
__global__ void k_tsel(const int* __restrict__ x, int* __restrict__ tsel,
                       int* __restrict__ padsel) {
  int b = threadIdx.x >> 3, j = threadIdx.x & 7;
  int c = 0;
  for (int t = j * 64; t < j * 64 + 64; ++t) c += (x[b * 512 + t] != 1) ? 1 : 0;
  c += __shfl_xor(c, 1);
  c += __shfl_xor(c, 2);
  c += __shfl_xor(c, 4);
  if (j == 0) {
    int ts = (c - 1) & 511;                        // len==0 wraps to T-1
    tsel[b] = ts;
    padsel[b] = (x[b * 512 + ts] == 1) ? 1 : 0;
  }
}

// ---------------- final logits: [64,1024] @ [8,1024]^T + b ----------------
__global__ void k_logits(const float* __restrict__ finalb, const float* __restrict__ Wout,
                         const float* __restrict__ bout, float* __restrict__ out) {
  int tid = threadIdx.x;
  for (int e = tid; e < 512; e += 256) {
    int b = e >> 3, o = e & 7;
    const float* f = finalb + (size_t)b * 1024;
    const float* w = Wout + (size_t)o * 1024;
    float s = 0.f;
    for (int k = 0; k < 1024; ++k) s += f[k] * w[k];
    out[e] = s + bout[o];
  }
}

// ================= SPLIT PATH: k_gemm (grid 256) =================
// zx[t][b][zcol], zcol gate-interleaved: zcol = col*4 + gate.
struct GSmem {
  union {
    struct { unsigned short A[128][72]; unsigned short Bt[256][72]; } g;
    struct { unsigned short zs[128][136]; } zst;
  } u;
  unsigned short pad[14336];          // -> 82 KB: force 1 wg/CU
};

__global__ __launch_bounds__(256, 1) void k_gemm(
    const int* __restrict__ x, const float* __restrict__ Wemb,
    const unsigned short* __restrict__ Wihb, const unsigned short* __restrict__ wembb,
    unsigned short* __restrict__ zxr) {
  __shared__ GSmem smem;
  const int wg = blockIdx.x, tid = threadIdx.x;
  const int wave = tid >> 6, lane = tid & 63;
  const int l15 = lane & 15, lg = lane >> 4;
  if (tid == 65535) smem.pad[0] = 0;
  const f32x4 fz = {0.f, 0.f, 0.f, 0.f};
  const int pmN = 256, npatch = pmN * 16;

  for (int p = wg; p < npatch; p += 256) {
    const int pm = p % pmN;                  // timesteps 2pm, 2pm+1
    const int n0 = (p / pmN) * 256;          // zcol base
    f32x4 acc[8][4];
#pragma unroll
    for (int mt = 0; mt < 8; ++mt)
#pragma unroll
      for (int nt = 0; nt < 4; ++nt) acc[mt][nt] = fz;

    for (int kc = 0; kc < 512; kc += 64) {
      __syncthreads();
      {  // stage A: gathered embedding rows ([128 m][64 k])
        int r = tid >> 1, half = (tid & 1) << 5;
        int t = pm * 2 + (r >> 6), b = r & 63;
        int erow = x[b * 512 + t];
        if (wembb) {
          const unsigned short* srcp = wembb + (size_t)erow * 512 + kc + half;
#pragma unroll
          for (int j = 0; j < 32; j += 8)
            *(uint4*)&smem.u.g.A[r][half + j] = *(const uint4*)(srcp + j);
        } else {
          const float* srcp = Wemb + (size_t)erow * 512 + kc + half;
#pragma unroll
          for (int j = 0; j < 32; j += 4) {
            float4 v = *(const float4*)(srcp + j);
            uint2 pk;
            pk.x = (unsigned)f2bf(v.x) | ((unsigned)f2bf(v.y) << 16);
            pk.y = (unsigned)f2bf(v.z) | ((unsigned)f2bf(v.w) << 16);
            *(uint2*)&smem.u.g.A[r][half + j] = pk;
          }
        }
      }
      {  // stage B: W_ih rows in gate-interleaved zcol order
        int zcx = n0 + tid;
        int wrow = (zcx & 3) * 1024 + (zcx >> 2);
        const unsigned short* srcp = Wihb + (size_t)wrow * 512 + kc;
#pragma unroll
        for (int j = 0; j < 64; j += 8)
          *(uint4*)&smem.u.g.Bt[tid][j] = *(const uint4*)(srcp + j);
      }
      __syncthreads();
#pragma unroll
      for (int ks = 0; ks < 64; ks += 32) {
        bf16x8 af[8];
#pragma unroll
        for (int mt = 0; mt < 8; ++mt)
          af[mt] = *(const bf16x8*)&smem.u.g.A[mt * 16 + l15][ks + (lg << 3)];
#pragma unroll
        for (int nt = 0; nt < 4; ++nt) {
          bf16x8 bfr =
              *(const bf16x8*)&smem.u.g.Bt[(wave * 4 + nt) * 16 + l15][ks + (lg << 3)];
#pragma unroll
          for (int mt = 0; mt < 8; ++mt)
            acc[mt][nt] = MFMA16(af[mt], bfr, acc[mt][nt]);
        }
      }
    }
    // store acc -> zx through LDS, two 128-col halves
#pragma unroll
    for (int h = 0; h < 2; ++h) {
      __syncthreads();
      if ((wave >> 1) == h) {
#pragma unroll
        for (int mt = 0; mt < 8; ++mt)
#pragma unroll
          for (int nt = 0; nt < 4; ++nt)
#pragma unroll
            for (int r = 0; r < 4; ++r)
              smem.u.zst.zs[mt * 16 + (lg << 2) + r][(wave & 1) * 64 + nt * 16 + l15] =
                  f2bf(acc[mt][nt][r]);
      }
      __syncthreads();
      int m = tid >> 1, qq = (tid & 1) << 6;
      int t2 = pm * 2 + (m >> 6), bb = m & 63;
      unsigned short* dst = zxr + ((size_t)(t2 * 64 + bb)) * 4096 + n0 + h * 128 + qq;
#pragma unroll
      for (int j = 0; j < 64; j += 8)
        *(uint4*)(dst + j) = *(const uint4*)&smem.u.zst.zs[m][qq + j];
    }
  }
}

// ================= SPLIT PATH: k_rec (grid 128, pure recurrence) =================
struct RSmem {
  unsigned short sW[32][1032];             // W_hh slice
  float z[64][33];                         // z redistribute
  unsigned short pad[5120];                // -> 82.7 KB: force 1 wg/CU
};

__global__ __launch_bounds__(256, 1) void k_rec(
    const float* __restrict__ bih, const float* __restrict__ bhh,
    const unsigned short* __restrict__ Whhb,
    unsigned short* __restrict__ hr, float* __restrict__ finalb,
    const int* __restrict__ tsel, const int* __restrict__ padsel,
    const unsigned short* __restrict__ zxr, unsigned* __restrict__ bar) {
  __shared__ RSmem smem;
  const int wg = blockIdx.x, tid = threadIdx.x;
  const int wave = tid >> 6, lane = tid & 63;
  const int l15 = lane & 15, lg = lane >> 4;
  if (tid == 65535) smem.pad[0] = 0;
  const f32x4 fz = {0.f, 0.f, 0.f, 0.f};

  for (int e = tid; e < 32 * 128; e += 256) {
    int n = e >> 7, kq = (e & 127) << 3;
    int grow = (n >> 3) * 1024 + wg * 8 + (n & 7);
    *(uint4*)&smem.sW[n][kq] = *(const uint4*)(Whhb + (size_t)grow * 1024 + kq);
  }
  const int q = tid & 3;
  const int my_b = tid >> 2;
  const int zc = wg * 8 + 2 * q;
  float biasv[4][2];
#pragma unroll
  for (int g = 0; g < 4; ++g)
#pragma unroll
    for (int c = 0; c < 2; ++c)
      biasv[g][c] = bih[g * 1024 + zc + c] + bhh[g * 1024 + zc + c];
  const int my_tsel = tsel[my_b];
  const int my_pad = padsel[my_b];
  const size_t hwe = (size_t)((my_b >> 4) * 32 + (wg >> 2)) * 512 +
                     (size_t)(wg & 3) * 128 + (size_t)(my_b & 15) * 8 + 2 * q;
  float cc0 = 0.f, cc1 = 0.f;
  unsigned bt = 0;

  AT_ST((unsigned*)hr + (wg * 256 + tid), 0u, __ATOMIC_RELAXED);
  flagbar(bar, wg, ++bt, 0);

  // prefetch zx for t=0 (gate-interleaved: 16B contiguous per thread)
  union { uint2 u2[2]; unsigned short s[8]; } vv;
  {
    const unsigned short* zr = zxr + (size_t)my_b * 4096 + zc * 4;
    vv.u2[0] = *(const uint2*)zr;
    vv.u2[1] = *(const uint2*)(zr + 4);
  }

  for (int t = 0; t < 512; ++t) {
    // ---- z_h = h_prev @ W_hh_slice^T; h in MFMA-fragment order ----
    const unsigned short* hp =
        hr + (size_t)(t & 15) * HSLOT + (size_t)wave * 16384 + (size_t)lane * 8;
    f32x4 r0 = fz, r1 = fz;
    bf16x8 af[32];
#pragma unroll
    for (int j = 0; j < 32; ++j) af[j] = *(const bf16x8*)(hp + (size_t)j * 512);
#pragma unroll
    for (int j = 0; j < 32; ++j) {
      int ks = j * 32;
      bf16x8 b0 = *(const bf16x8*)&smem.sW[l15][ks + (lg << 3)];
      bf16x8 b1 = *(const bf16x8*)&smem.sW[16 + l15][ks + (lg << 3)];
      r0 = MFMA16(af[j], b0, r0);
      r1 = MFMA16(af[j], b1, r1);
    }
#pragma unroll
    for (int r = 0; r < 4; ++r) {
      smem.z[wave * 16 + (lg << 2) + r][l15] = r0[r];
      smem.z[wave * 16 + (lg << 2) + r][16 + l15] = r1[r];
    }
    __syncthreads();

    int hc = 2 * q;
    float zi0 = smem.z[my_b][hc]          + biasv[0][0] + bf2f(vv.s[0]);
    float zf0 = smem.z[my_b][8 + hc]      + biasv[1][0] + bf2f(vv.s[1]);
    float zg0 = smem.z[my_b][16 + hc]     + biasv[2][0] + bf2f(vv.s[2]);
    float zo0 = smem.z[my_b][24 + hc]     + biasv[3][0] + bf2f(vv.s[3]);
    float zi1 = smem.z[my_b][hc + 1]      + biasv[0][1] + bf2f(vv.s[4]);
    float zf1 = smem.z[my_b][8 + hc + 1]  + biasv[1][1] + bf2f(vv.s[5]);
    float zg1 = smem.z[my_b][16 + hc + 1] + biasv[2][1] + bf2f(vv.s[6]);
    float zo1 = smem.z[my_b][24 + hc + 1] + biasv[3][1] + bf2f(vv.s[7]);

    cc0 = sigf(zf0) * cc0 + sigf(zi0) * tanh_(zg0);
    cc1 = sigf(zf1) * cc1 + sigf(zi1) * tanh_(zg1);
    float h0 = sigf(zo0) * tanh_(cc0);
    float h1 = sigf(zo1) * tanh_(cc1);

    if (t == my_tsel) {
      finalb[(size_t)my_b * 1024 + zc]     = my_pad ? 0.f : h0;
      finalb[(size_t)my_b * 1024 + zc + 1] = my_pad ? 0.f : h1;
    }
    unsigned hp32 = (unsigned)f2bf(h0) | ((unsigned)f2bf(h1) << 16);
    AT_ST((unsigned*)(hr + (size_t)((t + 1) & 15) * HSLOT + hwe), hp32,
          __ATOMIC_RELAXED);

    if (t + 1 < 512) {                  // prefetch next step's zx
      const unsigned short* zn = zxr + ((size_t)(t + 1) * 64 + my_b) * 4096 + zc * 4;
      vv.u2[0] = *(const uint2*)zn;
      vv.u2[1] = *(const uint2*)(zn + 4);
    }
    flagbar(bar, wg, ++bt, (t & 15) == 6);   // inv once per 16 steps (ring refresh)
  }
}

// ================= FUSED FALLBACK (R8 k_main, ring mode) =================
struct SmemT {
  unsigned short sW[32][1032];
  union {
    struct { unsigned short A[128][72]; unsigned short Bt[256][72]; } g;
    struct { float z[64][33]; } rec;
    struct { unsigned short zs[128][136]; } zst;
  } u;
};

__global__ __launch_bounds__(256, 1) void k_main(
    const int* __restrict__ x, const float* __restrict__ Wemb,
    const float* __restrict__ bih, const float* __restrict__ bhh,
    const unsigned short* __restrict__ Wihb, const unsigned short* __restrict__ Whhb,
    const unsigned short* __restrict__ wembb,
    unsigned short* __restrict__ hr, float* __restrict__ finalb,
    const int* __restrict__ tsel, const int* __restrict__ padsel,
    unsigned short* __restrict__ zxr, unsigned* __restrict__ bar, int chunkT) {
  __shared__ SmemT smem;
  const int wg = blockIdx.x, tid = threadIdx.x;
  const int wave = tid >> 6, lane = tid & 63;
  const int l15 = lane & 15, lg = lane >> 4;
  unsigned* gemm_done = bar + 512;
  unsigned* rec_done  = bar + 576;
  const f32x4 fz = {0.f, 0.f, 0.f, 0.f};
  const int nChunks = 512 / chunkT;
  const size_t slotE = (size_t)chunkT * 64 * 4096;

  if (wg < 128) {
    for (int e = tid; e < 32 * 128; e += 256) {
      int n = e >> 7, kq = (e & 127) << 3;
      int grow = (n >> 3) * 1024 + wg * 8 + (n & 7);
      *(uint4*)&smem.sW[n][kq] = *(const uint4*)(Whhb + (size_t)grow * 1024 + kq);
    }
    const int q = tid & 3;
    const int my_b = tid >> 2;
    const int zc = wg * 8 + 2 * q;
    float biasv[4][2];
#pragma unroll
    for (int g = 0; g < 4; ++g)
#pragma unroll
      for (int c = 0; c < 2; ++c)
        biasv[g][c] = bih[g * 1024 + zc + c] + bhh[g * 1024 + zc + c];
    const int my_tsel = tsel[my_b];
    const int my_pad = padsel[my_b];
    const size_t hwe = (size_t)((my_b >> 4) * 32 + (wg >> 2)) * 512 +
                       (size_t)(wg & 3) * 128 + (size_t)(my_b & 15) * 8 + 2 * q;
    float cc0 = 0.f, cc1 = 0.f;
    unsigned bt = 0;
    AT_ST((unsigned*)hr + (wg * 256 + tid), 0u, __ATOMIC_RELAXED);
    gbar_rec(bar, wg, ++bt);

    for (int ch = 0; ch < nChunks; ++ch) {
      const int t0 = ch * chunkT;
      const unsigned short* zxbase = zxr + (size_t)(ch & 1) * slotE;
      if (tid == 0) {
        while (AT_LD(gemm_done, __ATOMIC_RELAXED) < (unsigned)(ch + 1))
          __builtin_amdgcn_s_sleep(4);
        (void)AT_LD(gemm_done, __ATOMIC_ACQUIRE);
        asm volatile("" ::: "memory");
      }
      __syncthreads();
      union { uint2 u2[2]; unsigned short s[8]; } vv;
      {
        const unsigned short* zr = zxbase + (size_t)my_b * 4096 + zc * 4;
        vv.u2[0] = *(const uint2*)zr;
        vv.u2[1] = *(const uint2*)(zr + 4);
      }
      for (int tl = 0; tl < chunkT; ++tl) {
        const int t = t0 + tl;
        const unsigned short* hp =
            hr + (size_t)(t & 15) * HSLOT + (size_t)wave * 16384 + (size_t)lane * 8;
        f32x4 r0 = fz, r1 = fz;
        bf16x8 af[32];
#pragma unroll
        for (int j = 0; j < 32; ++j) af[j] = *(const bf16x8*)(hp + (size_t)j * 512);
#pragma unroll
        for (int j = 0; j < 32; ++j) {
          int ks = j * 32;
          bf16x8 b0 = *(const bf16x8*)&smem.sW[l15][ks + (lg << 3)];
          bf16x8 b1 = *(const bf16x8*)&smem.sW[16 + l15][ks + (lg << 3)];
          r0 = MFMA16(af[j], b0, r0);
          r1 = MFMA16(af[j], b1, r1);
        }
#pragma unroll
        for (int r = 0; r < 4; ++r) {
          smem.u.rec.z[wave * 16 + (lg << 2) + r][l15] = r0[r];
          smem.u.rec.z[wave * 16 + (lg << 2) + r][16 + l15] = r1[r];
        }
        __syncthreads();
        int hc = 2 * q;
        float zi0 = smem.u.rec.z[my_b][hc]          + biasv[0][0] + bf2f(vv.s[0]);
        float zf0 = smem.u.rec.z[my_b][8 + hc]      + biasv[1][0] + bf2f(vv.s[1]);
        float zg0 = smem.u.rec.z[my_b][16 + hc]     + biasv[2][0] + bf2f(vv.s[2]);
        float zo0 = smem.u.rec.z[my_b][24 + hc]     + biasv[3][0] + bf2f(vv.s[3]);
        float zi1 = smem.u.rec.z[my_b][hc + 1]      + biasv[0][1] + bf2f(vv.s[4]);
        float zf1 = smem.u.rec.z[my_b][8 + hc + 1]  + biasv[1][1] + bf2f(vv.s[5]);
        float zg1 = smem.u.rec.z[my_b][16 + hc + 1] + biasv[2][1] + bf2f(vv.s[6]);
        float zo1 = smem.u.rec.z[my_b][24 + hc + 1] + biasv[3][1] + bf2f(vv.s[7]);
        cc0 = sigf(zf0) * cc0 + sigf(zi0) * tanh_(zg0);
        cc1 = sigf(zf1) * cc1 + sigf(zi1) * tanh_(zg1);
        float h0 = sigf(zo0) * tanh_(cc0);
        float h1 = sigf(zo1) * tanh_(cc1);
        if (t == my_tsel) {
          finalb[(size_t)my_b * 1024 + zc]     = my_pad ? 0.f : h0;
          finalb[(size_t)my_b * 1024 + zc + 1] = my_pad ? 0.f : h1;
        }
        unsigned hp32 = (unsigned)f2bf(h0) | ((unsigned)f2bf(h1) << 16);
        AT_ST((unsigned*)(hr + (size_t)((t + 1) & 15) * HSLOT + hwe), hp32,
              __ATOMIC_RELAXED);
        if (tl + 1 < chunkT) {
          const unsigned short* zn =
              zxbase + (size_t)((tl + 1) * 64 + my_b) * 4096 + zc * 4;
          vv.u2[0] = *(const uint2*)zn;
          vv.u2[1] = *(const uint2*)(zn + 4);
        }
        gbar_rec(bar, wg, ++bt);
      }
      if (wg == 0 && tid == 0) AT_ST(rec_done, (unsigned)(ch + 1), __ATOMIC_RELAXED);
    }
  } else {
    const int gw = wg - 128;
    unsigned gt = 0;
    for (int ch = 0; ch < nChunks; ++ch) {
      if (tid == 0 && ch >= 2) {
        while (AT_LD(rec_done, __ATOMIC_RELAXED) < (unsigned)(ch - 1))
          __builtin_amdgcn_s_sleep(4);
        asm volatile("" ::: "memory");
      }
      __syncthreads();
      const int t0 = ch * chunkT;
      unsigned short* zx = zxr + (size_t)(ch & 1) * slotE;
      const int pmN = chunkT >> 1;
      const int npatch = pmN * 16;
      for (int p = gw; p < npatch; p += 128) {
        const int pm = p % pmN;
        const int n0 = (p / pmN) * 256;
        f32x4 acc[8][4];
#pragma unroll
        for (int mt = 0; mt < 8; ++mt)
#pragma unroll
          for (int nt = 0; nt < 4; ++nt) acc[mt][nt] = fz;
        for (int kc = 0; kc < 512; kc += 64) {
          __syncthreads();
          {
            int r = tid >> 1, half = (tid & 1) << 5;
            int tl = pm * 2 + (r >> 6), b = r & 63;
            int erow = x[b * 512 + t0 + tl];
            if (wembb) {
              const unsigned short* srcp = wembb + (size_t)erow * 512 + kc + half;
#pragma unroll
              for (int j = 0; j < 32; j += 8)
                *(uint4*)&smem.u.g.A[r][half + j] = *(const uint4*)(srcp + j);
            } else {
              const float* srcp = Wemb + (size_t)erow * 512 + kc + half;
#pragma unroll
              for (int j = 0; j < 32; j += 4) {
                float4 v = *(const float4*)(srcp + j);
                uint2 pk;
                pk.x = (unsigned)f2bf(v.x) | ((unsigned)f2bf(v.y) << 16);
                pk.y = (unsigned)f2bf(v.z) | ((unsigned)f2bf(v.w) << 16);
                *(uint2*)&smem.u.g.A[r][half + j] = pk;
              }
            }
          }
          {
            int zcx = n0 + tid;
            int wrow = (zcx & 3) * 1024 + (zcx >> 2);
            const unsigned short* srcp = Wihb + (size_t)wrow * 512 + kc;
#pragma unroll
            for (int j = 0; j < 64; j += 8)
              *(uint4*)&smem.u.g.Bt[tid][j] = *(const uint4*)(srcp + j);
          }
          __syncthreads();
#pragma unroll
          for (int ks = 0; ks < 64; ks += 32) {
            bf16x8 af[8];
#pragma unroll
            for (int mt = 0; mt < 8; ++mt)
              af[mt] = *(const bf16x8*)&smem.u.g.A[mt * 16 + l15][ks + (lg << 3)];
#pragma unroll
            for (int nt = 0; nt < 4; ++nt) {
              bf16x8 bfr =
                  *(const bf16x8*)&smem.u.g.Bt[(wave * 4 + nt) * 16 + l15][ks + (lg << 3)];
#pragma unroll
              for (int mt = 0; mt < 8; ++mt)
                acc[mt][nt] = MFMA16(af[mt], bfr, acc[mt][nt]);
            }
          }
        }
#pragma unroll
        for (int h = 0; h < 2; ++h) {
          __syncthreads();
          if ((wave >> 1) == h) {
#pragma unroll
            for (int mt = 0; mt < 8; ++mt)
#pragma unroll
              for (int nt = 0; nt < 4; ++nt)
#pragma unroll
                for (int r = 0; r < 4; ++r)
                  smem.u.zst.zs[mt * 16 + (lg << 2) + r][(wave & 1) * 64 + nt * 16 + l15] =
                      f2bf(acc[mt][nt][r]);
          }
          __syncthreads();
          int m = tid >> 1, qq = (tid & 1) << 6;
          int tl2 = pm * 2 + (m >> 6), bb = m & 63;
          unsigned short* dst = zx + ((size_t)(tl2 * 64 + bb)) * 4096 + n0 + h * 128 + qq;
#pragma unroll
          for (int j = 0; j < 64; j += 8)
            *(uint4*)(dst + j) = *(const uint4*)&smem.u.zst.zs[m][qq + j];
        }
      }
      gbar_gemm(bar, ++gt);
      if (wg == 128 && tid == 0) AT_ST(gemm_done, gt, __ATOMIC_RELAXED);
    }
  }
}

extern "C" void kernel_launch(void* const* d_in, const int* in_sizes, int n_in,
                              void* d_out, int out_size, void* d_ws, size_t ws_size,
                              hipStream_t stream) {
  (void)in_sizes; (void)n_in; (void)out_size;
  const int*   x    = (const int*)  d_in[0];
  const float* Wemb = (const float*)d_in[1];
  const float* Wih  = (const float*)d_in[2];
  const float* Whh  = (const float*)d_in[3];
  const float* bih  = (const float*)d_in[4];
  const float* bhh  = (const float*)d_in[5];
  const float* Wout = (const float*)d_in[6];
  const float* bout = (const float*)d_in[7];
  float* out = (float*)d_out;
  char* ws = (char*)d_ws;

  constexpr size_t OFF_WIH = 0;
  constexpr size_t OFF_WHH = OFF_WIH + (size_t)4096 * 512 * 2;    //  4 MB
  constexpr size_t OFF_HR  = OFF_WHH + (size_t)4096 * 1024 * 2;   // +8 MB
  constexpr size_t OFF_FIN = OFF_HR + (size_t)16 * HSLOT * 2;     // +2.06 MB
  constexpr size_t OFF_TS  = OFF_FIN + (size_t)64 * 1024 * 4;     // +256 KB
  constexpr size_t OFF_PS  = OFF_TS + 4096;
  constexpr size_t OFF_BAR = OFF_PS + 4096;
  constexpr size_t OFF_WEB = OFF_BAR + 40960;                     // 40 KB barrier zone
  constexpr size_t WEB_SZ  = (size_t)32000 * 512 * 2;             // 32 MB
  constexpr size_t ZX_FULL = (size_t)512 * 64 * 4096 * 2;         // 256 MB

  bool split = (OFF_WEB + WEB_SZ + ZX_FULL <= ws_size);
  int chunkT = 16;
  bool wbf = true;
  if (!split) {
    if (OFF_WEB + WEB_SZ + (size_t)2 * 16 * 64 * 4096 * 2 <= ws_size) {
      // ring mode with bf16 Wemb
    } else if (OFF_WEB + (size_t)2 * 16 * 64 * 4096 * 2 <= ws_size) {
      wbf = false;
    } else {
      wbf = false;
      while (chunkT > 2 && OFF_WEB + (size_t)2 * chunkT * 64 * 4096 * 2 > ws_size)
        chunkT >>= 1;
    }
  }
  const size_t OFF_ZX = OFF_WEB + (wbf ? WEB_SZ : 0);

  unsigned short* wihb  = (unsigned short*)(ws + OFF_WIH);
  unsigned short* whhb  = (unsigned short*)(ws + OFF_WHH);
  unsigned short* hr    = (unsigned short*)(ws + OFF_HR);
  float* finalb         = (float*)(ws + OFF_FIN);
  int* tsel             = (int*)(ws + OFF_TS);
  int* padsel           = (int*)(ws + OFF_PS);
  unsigned* bar         = (unsigned*)(ws + OFF_BAR);
  unsigned short* wembb = wbf ? (unsigned short*)(ws + OFF_WEB) : (unsigned short*)nullptr;
  unsigned short* zxr   = (unsigned short*)(ws + OFF_ZX);

  hipMemsetAsync(ws + OFF_BAR, 0, 40960, stream);
  k_conv<<<2048, 256, 0, stream>>>(Wih, Whh, Wemb, wihb, whhb, wembb);
  k_tsel<<<1, 512, 0, stream>>>(x, tsel, padsel);
  if (split) {
    k_gemm<<<256, 256, 0, stream>>>(x, Wemb, wihb, wembb, zxr);
    k_rec<<<128, 256, 0, stream>>>(bih, bhh, whhb, hr, finalb, tsel, padsel, zxr, bar);
  } else {
    k_main<<<256, 256, 0, stream>>>(x, Wemb, bih, bhh, wihb, whhb, wembb, hr, finalb,
                                    tsel, padsel, zxr, bar, chunkT);
  }
  k_logits<<<1, 256, 0, stream>>>(finalb, Wout, bout, out);
}

// Round 10
// 3234.798 us; speedup vs baseline: 1.0281x; 1.0281x over previous
//
#include <hip/hip_runtime.h>

typedef short bf16x8 __attribute__((ext_vector_type(8)));
typedef float f32x4  __attribute__((ext_vector_type(4)));
typedef unsigned long long u64;

#define MFMA16(a, b, c) __builtin_amdgcn_mfma_f32_16x16x32_bf16((a), (b), (c), 0, 0, 0)
#define AT_LD(p, o)    __hip_atomic_load((p), (o), __HIP_MEMORY_SCOPE_AGENT)
#define AT_ST(p, v, o) __hip_atomic_store((p), (v), (o), __HIP_MEMORY_SCOPE_AGENT)
#define AT_ADD(p, v, o) __hip_atomic_fetch_add((p), (v), (o), __HIP_MEMORY_SCOPE_AGENT)

#define HSLOT 67584      // h ring slot stride in bf16 elems (128KB + 4KB pad)

// barrier zone layout (words): flags[wg]=wg*64 (0..8128), gen=8192,
// gemm tree: 8256(cnt) 8320(gen), gemm_done=8384, rec_done=8448
__device__ __forceinline__ unsigned short f2bf(float f) {
  union { float f; unsigned u; } v; v.f = f;
  unsigned u = v.u;
  u += 0x7fffu + ((u >> 16) & 1u);
  return (unsigned short)(u >> 16);
}
__device__ __forceinline__ float bf2f(unsigned short h) {
  union { unsigned u; float f; } v; v.u = ((unsigned)h) << 16;
  return v.f;
}
__device__ __forceinline__ float sigf(float x) { return 1.f / (1.f + __expf(-x)); }
__device__ __forceinline__ float tanh_(float x) {
  x = fminf(15.f, fmaxf(-15.f, x));
  float e = __expf(2.f * x);
  return (e - 1.f) / (e + 1.f);
}

// ---- flag-array barrier for the 128 rec wgs: zero atomic serialization ----
__device__ __forceinline__ void flagbar(unsigned* bar, int wg, unsigned target) {
  unsigned* gen = bar + 8192;
  __syncthreads();                       // all work + h sc1 stores drained (vmcnt)
  if (threadIdx.x == 0) {
    asm volatile("" ::: "memory");
    AT_ST(bar + wg * 64, target, __ATOMIC_RELAXED);
  }
  if (wg == 0) {
    if (threadIdx.x < 128) {
      while (AT_LD(bar + threadIdx.x * 64, __ATOMIC_RELAXED) < target)
        __builtin_amdgcn_s_sleep(1);
    }
    __syncthreads();
    if (threadIdx.x == 0) AT_ST(gen, target, __ATOMIC_RELAXED);
  } else {
    if (threadIdx.x == 0) {
      while (AT_LD(gen, __ATOMIC_RELAXED) < target) __builtin_amdgcn_s_sleep(1);
    }
  }
  __syncthreads();
}

// ---- per-chunk release barrier for the 128 GEMM wgs ----
__device__ __forceinline__ void gbar_gemm(unsigned* bar, unsigned target) {
  __syncthreads();
  if (threadIdx.x == 0) {
    unsigned arr = AT_ADD(bar + 8256, 1u, __ATOMIC_RELEASE);  // vmcnt drain + L2 wb
    if (arr == target * 128u - 1u) AT_ST(bar + 8320, target, __ATOMIC_RELEASE);
    while (AT_LD(bar + 8320, __ATOMIC_RELAXED) < target) __builtin_amdgcn_s_sleep(4);
    asm volatile("" ::: "memory");
  }
  __syncthreads();
}

// ---------------- weight conversion fp32 -> bf16 ----------------
__global__ void k_conv(const float* __restrict__ wih, const float* __restrict__ whh,
                       const float* __restrict__ wemb,
                       unsigned short* __restrict__ oih, unsigned short* __restrict__ ohh,
                       unsigned short* __restrict__ oemb) {
  const size_t NIH = (size_t)4096 * 512, NHH = (size_t)4096 * 1024;
  const size_t NE = (size_t)32000 * 512;
  size_t i0 = ((size_t)blockIdx.x * blockDim.x + threadIdx.x) * 4;
  size_t gs = (size_t)gridDim.x * blockDim.x * 4;
  for (size_t j = i0; j < NIH; j += gs) {
    float4 v = *(const float4*)(wih + j);
    uint2 pk;
    pk.x = (unsigned)f2bf(v.x) | ((unsigned)f2bf(v.y) << 16);
    pk.y = (unsigned)f2bf(v.z) | ((unsigned)f2bf(v.w) << 16);
    *(uint2*)(oih + j) = pk;
  }
  for (size_t j = i0; j < NHH; j += gs) {
    float4 v = *(const float4*)(whh + j);
    uint2 pk;
    pk.x = (unsigned)f2bf(v.x) | ((unsigned)f2bf(v.y) << 16);
    pk.y = (unsigned)f2bf(v.z) | ((unsigned)f2bf(v.w) << 16);
    *(uint2*)(ohh + j) = pk;
  }
  if (oemb)
    for (size_t j = i0; j < NE; j += gs) {
      float4 v = *(const float4*)(wemb + j);
      uint2 pk;
      pk.x = (unsigned)f2bf(v.x) | ((unsigned)f2bf(v.y) << 16);
      pk.y = (unsigned)f2bf(v.z) | ((unsigned)f2bf(v.w) << 16);
      *(uint2*)(oemb + j) = pk;
    }
}

// ---------------- lengths / selection index ----------------
__global__ void k_tsel(const int* __restrict__ x, int* __restrict__ tsel,
                       int* __restrict__ padsel) {
  int b = threadIdx.x >> 3, j = threadIdx.x & 7;
  int c = 0;
  for (int t = j * 64; t < j * 64 + 64; ++t) c += (x[b * 512 + t] != 1) ? 1 : 0;
  c += __shfl_xor(c, 1);
  c += __shfl_xor(c, 2);
  c += __shfl_xor(c, 4);
  if (j == 0) {
    int ts = (c - 1) & 511;                        // len==0 wraps to T-1
    tsel[b] = ts;
    padsel[b] = (x[b * 512 + ts] == 1) ? 1 : 0;
  }
}

// ---------------- final logits: [64,1024] @ [8,1024]^T + b ----------------
__global__ void k_logits(const float* __restrict__ finalb, const float* __restrict__ Wout,
                         const float* __restrict__ bout, float* __restrict__ out) {
  int tid = threadIdx.x;
  for (int e = tid; e < 512; e += 256) {
    int b = e >> 3, o = e & 7;
    const float* f = finalb + (size_t)b * 1024;
    const float* w = Wout + (size_t)o * 1024;
    float s = 0.f;
    for (int k = 0; k < 1024; ++k) s += f[k] * w[k];
    out[e] = s + bout[o];
  }
}

// ---------------- main kernel: 256 wgs = 128 rec + 128 GEMM ----------------
// zx ring has NSLOT 8MB slots; GEMM front-loads and EXITS when all 32 chunks done.
struct SmemT {
  unsigned short sW[32][1032];
  union {
    struct { unsigned short A[128][72]; unsigned short Bt[256][72]; } g;
    struct { float z[64][33]; } rec;
    struct { unsigned short zs[128][136]; } zst;
  } u;
};

__global__ __launch_bounds__(256, 1) void k_main(
    const int* __restrict__ x, const float* __restrict__ Wemb,
    const float* __restrict__ bih, const float* __restrict__ bhh,
    const unsigned short* __restrict__ Wihb, const unsigned short* __restrict__ Whhb,
    const unsigned short* __restrict__ wembb,
    unsigned short* __restrict__ hr, float* __restrict__ finalb,
    const int* __restrict__ tsel, const int* __restrict__ padsel,
    unsigned short* __restrict__ zxr, unsigned* __restrict__ bar, int chunkT,
    int nslot) {
  __shared__ SmemT smem;
  const int wg = blockIdx.x, tid = threadIdx.x;
  const int wave = tid >> 6, lane = tid & 63;
  const int l15 = lane & 15, lg = lane >> 4;
  unsigned* gemm_done = bar + 8384;
  unsigned* rec_done  = bar + 8448;
  const f32x4 fz = {0.f, 0.f, 0.f, 0.f};
  const int nChunks = 512 / chunkT;
  const size_t slotE = (size_t)chunkT * 64 * 4096;

  if (wg < 128) {
    // ================= RECURRENT ROLE =================
    for (int e = tid; e < 32 * 128; e += 256) {
      int n = e >> 7, kq = (e & 127) << 3;
      int grow = (n >> 3) * 1024 + wg * 8 + (n & 7);
      *(uint4*)&smem.sW[n][kq] = *(const uint4*)(Whhb + (size_t)grow * 1024 + kq);
    }
    const int q = tid & 3;
    const int my_b = tid >> 2;
    const int zc = wg * 8 + 2 * q;
    float biasv[4][2];
#pragma unroll
    for (int g = 0; g < 4; ++g)
#pragma unroll
      for (int c = 0; c < 2; ++c)
        biasv[g][c] = bih[g * 1024 + zc + c] + bhh[g * 1024 + zc + c];
    const int my_tsel = tsel[my_b];
    const int my_pad = padsel[my_b];
    const size_t hwe = (size_t)((my_b >> 4) * 32 + (wg >> 2)) * 512 +
                       (size_t)(wg & 3) * 128 + (size_t)(my_b & 15) * 8 + 2 * q;
    float cc0 = 0.f, cc1 = 0.f;
    unsigned bt = 0;
    AT_ST((unsigned*)hr + (wg * 256 + tid), 0u, __ATOMIC_RELAXED);
    flagbar(bar, wg, ++bt);

    for (int ch = 0; ch < nChunks; ++ch) {
      const int t0 = ch * chunkT;
      const unsigned short* zxbase = zxr + (size_t)(ch % nslot) * slotE;
      if (tid == 0) {      // wait zx chunk; ONE acquire-inv per chunk (h-ring refresh too)
        while (AT_LD(gemm_done, __ATOMIC_RELAXED) < (unsigned)(ch + 1))
          __builtin_amdgcn_s_sleep(2);
        (void)AT_LD(gemm_done, __ATOMIC_ACQUIRE);
        asm volatile("" ::: "memory");
      }
      __syncthreads();
      union { uint2 u2[2]; unsigned short s[8]; } vv;
      {
        const unsigned short* zr = zxbase + (size_t)my_b * 4096 + zc * 4;
        vv.u2[0] = *(const uint2*)zr;
        vv.u2[1] = *(const uint2*)(zr + 4);
      }
      for (int tl = 0; tl < chunkT; ++tl) {
        const int t = t0 + tl;
        const unsigned short* hp =
            hr + (size_t)(t & 15) * HSLOT + (size_t)wave * 16384 + (size_t)lane * 8;
        f32x4 r0 = fz, r1 = fz;
        bf16x8 af[32];
#pragma unroll
        for (int j = 0; j < 32; ++j) af[j] = *(const bf16x8*)(hp + (size_t)j * 512);
#pragma unroll
        for (int j = 0; j < 32; ++j) {
          int ks = j * 32;
          bf16x8 b0 = *(const bf16x8*)&smem.sW[l15][ks + (lg << 3)];
          bf16x8 b1 = *(const bf16x8*)&smem.sW[16 + l15][ks + (lg << 3)];
          r0 = MFMA16(af[j], b0, r0);
          r1 = MFMA16(af[j], b1, r1);
        }
#pragma unroll
        for (int r = 0; r < 4; ++r) {
          smem.u.rec.z[wave * 16 + (lg << 2) + r][l15] = r0[r];
          smem.u.rec.z[wave * 16 + (lg << 2) + r][16 + l15] = r1[r];
        }
        __syncthreads();
        int hc = 2 * q;
        float zi0 = smem.u.rec.z[my_b][hc]          + biasv[0][0] + bf2f(vv.s[0]);
        float zf0 = smem.u.rec.z[my_b][8 + hc]      + biasv[1][0] + bf2f(vv.s[1]);
        float zg0 = smem.u.rec.z[my_b][16 + hc]     + biasv[2][0] + bf2f(vv.s[2]);
        float zo0 = smem.u.rec.z[my_b][24 + hc]     + biasv[3][0] + bf2f(vv.s[3]);
        float zi1 = smem.u.rec.z[my_b][hc + 1]      + biasv[0][1] + bf2f(vv.s[4]);
        float zf1 = smem.u.rec.z[my_b][8 + hc + 1]  + biasv[1][1] + bf2f(vv.s[5]);
        float zg1 = smem.u.rec.z[my_b][16 + hc + 1] + biasv[2][1] + bf2f(vv.s[6]);
        float zo1 = smem.u.rec.z[my_b][24 + hc + 1] + biasv[3][1] + bf2f(vv.s[7]);
        cc0 = sigf(zf0) * cc0 + sigf(zi0) * tanh_(zg0);
        cc1 = sigf(zf1) * cc1 + sigf(zi1) * tanh_(zg1);
        float h0 = sigf(zo0) * tanh_(cc0);
        float h1 = sigf(zo1) * tanh_(cc1);
        if (t == my_tsel) {
          finalb[(size_t)my_b * 1024 + zc]     = my_pad ? 0.f : h0;
          finalb[(size_t)my_b * 1024 + zc + 1] = my_pad ? 0.f : h1;
        }
        unsigned hp32 = (unsigned)f2bf(h0) | ((unsigned)f2bf(h1) << 16);
        AT_ST((unsigned*)(hr + (size_t)((t + 1) & 15) * HSLOT + hwe), hp32,
              __ATOMIC_RELAXED);
        if (tl + 1 < chunkT) {
          const unsigned short* zn =
              zxbase + (size_t)((tl + 1) * 64 + my_b) * 4096 + zc * 4;
          vv.u2[0] = *(const uint2*)zn;
          vv.u2[1] = *(const uint2*)(zn + 4);
        }
        flagbar(bar, wg, ++bt);
      }
      if (wg == 0 && tid == 0) AT_ST(rec_done, (unsigned)(ch + 1), __ATOMIC_RELAXED);
    }
  } else {
    // ============ GEMM ROLE (front-loads nslot chunks, then trickles; exits) ========
    const int gw = wg - 128;
    unsigned gt = 0;
    for (int ch = 0; ch < nChunks; ++ch) {
      // slot ch%nslot reusable only after rec consumed chunk ch-nslot
      if (tid == 0 && ch >= nslot) {
        while (AT_LD(rec_done, __ATOMIC_RELAXED) < (unsigned)(ch - nslot + 1))
          __builtin_amdgcn_s_sleep(8);
        asm volatile("" ::: "memory");
      }
      __syncthreads();
      const int t0 = ch * chunkT;
      unsigned short* zx = zxr + (size_t)(ch % nslot) * slotE;
      const int pmN = chunkT >> 1;
      const int npatch = pmN * 16;
      for (int p = gw; p < npatch; p += 128) {
        const int pm = p % pmN;
        const int n0 = (p / pmN) * 256;
        f32x4 acc[8][4];
#pragma unroll
        for (int mt = 0; mt < 8; ++mt)
#pragma unroll
          for (int nt = 0; nt < 4; ++nt) acc[mt][nt] = fz;
        for (int kc = 0; kc < 512; kc += 64) {
          __syncthreads();
          {
            int r = tid >> 1, half = (tid & 1) << 5;
            int tl = pm * 2 + (r >> 6), b = r & 63;
            int erow = x[b * 512 + t0 + tl];
            if (wembb) {
              const unsigned short* srcp = wembb + (size_t)erow * 512 + kc + half;
#pragma unroll
              for (int j = 0; j < 32; j += 8)
                *(uint4*)&smem.u.g.A[r][half + j] = *(const uint4*)(srcp + j);
            } else {
              const float* srcp = Wemb + (size_t)erow * 512 + kc + half;
#pragma unroll
              for (int j = 0; j < 32; j += 4) {
                float4 v = *(const float4*)(srcp + j);
                uint2 pk;
                pk.x = (unsigned)f2bf(v.x) | ((unsigned)f2bf(v.y) << 16);
                pk.y = (unsigned)f2bf(v.z) | ((unsigned)f2bf(v.w) << 16);
                *(uint2*)&smem.u.g.A[r][half + j] = pk;
              }
            }
          }
          {
            int zcx = n0 + tid;
            int wrow = (zcx & 3) * 1024 + (zcx >> 2);
            const unsigned short* srcp = Wihb + (size_t)wrow * 512 + kc;
#pragma unroll
            for (int j = 0; j < 64; j += 8)
              *(uint4*)&smem.u.g.Bt[tid][j] = *(const uint4*)(srcp + j);
          }
          __syncthreads();
#pragma unroll
          for (int ks = 0; ks < 64; ks += 32) {
            bf16x8 af[8];
#pragma unroll
            for (int mt = 0; mt < 8; ++mt)
              af[mt] = *(const bf16x8*)&smem.u.g.A[mt * 16 + l15][ks + (lg << 3)];
#pragma unroll
            for (int nt = 0; nt < 4; ++nt) {
              bf16x8 bfr =
                  *(const bf16x8*)&smem.u.g.Bt[(wave * 4 + nt) * 16 + l15][ks + (lg << 3)];
#pragma unroll
              for (int mt = 0; mt < 8; ++mt)
                acc[mt][nt] = MFMA16(af[mt], bfr, acc[mt][nt]);
            }
          }
        }
#pragma unroll
        for (int h = 0; h < 2; ++h) {
          __syncthreads();
          if ((wave >> 1) == h) {
#pragma unroll
            for (int mt = 0; mt < 8; ++mt)
#pragma unroll
              for (int nt = 0; nt < 4; ++nt)
#pragma unroll
                for (int r = 0; r < 4; ++r)
                  smem.u.zst.zs[mt * 16 + (lg << 2) + r][(wave & 1) * 64 + nt * 16 + l15] =
                      f2bf(acc[mt][nt][r]);
          }
          __syncthreads();
          int m = tid >> 1, qq = (tid & 1) << 6;
          int tl2 = pm * 2 + (m >> 6), bb = m & 63;
          unsigned short* dst = zx + ((size_t)(tl2 * 64 + bb)) * 4096 + n0 + h * 128 + qq;
#pragma unroll
          for (int j = 0; j < 64; j += 8)
            *(uint4*)(dst + j) = *(const uint4*)&smem.u.zst.zs[m][qq + j];
        }
      }
      gbar_gemm(bar, ++gt);
      if (wg == 128 && tid == 0) AT_ST(gemm_done, gt, __ATOMIC_RELAXED);
    }
    // all chunks published -> GEMM wgs exit, freeing 128 CUs for rec
  }
}

extern "C" void kernel_launch(void* const* d_in, const int* in_sizes, int n_in,
                              void* d_out, int out_size, void* d_ws, size_t ws_size,
                              hipStream_t stream) {
  (void)in_sizes; (void)n_in; (void)out_size;
  const int*   x    = (const int*)  d_in[0];
  const float* Wemb = (const float*)d_in[1];
  const float* Wih  = (const float*)d_in[2];
  const float* Whh  = (const float*)d_in[3];
  const float* bih  = (const float*)d_in[4];
  const float* bhh  = (const float*)d_in[5];
  const float* Wout = (const float*)d_in[6];
  const float* bout = (const float*)d_in[7];
  float* out = (float*)d_out;
  char* ws = (char*)d_ws;

  constexpr size_t OFF_WIH = 0;
  constexpr size_t OFF_WHH = OFF_WIH + (size_t)4096 * 512 * 2;    //  4 MB
  constexpr size_t OFF_HR  = OFF_WHH + (size_t)4096 * 1024 * 2;   // +8 MB
  constexpr size_t OFF_FIN = OFF_HR + (size_t)16 * HSLOT * 2;     // +2.06 MB
  constexpr size_t OFF_TS  = OFF_FIN + (size_t)64 * 1024 * 4;     // +256 KB
  constexpr size_t OFF_PS  = OFF_TS + 4096;
  constexpr size_t OFF_BAR = OFF_PS + 4096;
  constexpr size_t OFF_WEB = OFF_BAR + 40960;                     // 40 KB barrier zone
  constexpr size_t WEB_SZ  = (size_t)32000 * 512 * 2;             // 32 MB
  constexpr size_t SLOT_SZ = (size_t)16 * 64 * 4096 * 2;          // 8 MB per chunk slot

  int chunkT = 16;
  bool wbf = true;
  int nslot = 2;
  if (OFF_WEB + WEB_SZ + 2 * SLOT_SZ <= ws_size) {
    nslot = (int)((ws_size - OFF_WEB - WEB_SZ) / SLOT_SZ);
    if (nslot > 32) nslot = 32;
  } else if (OFF_WEB + 2 * SLOT_SZ <= ws_size) {
    wbf = false;
    nslot = (int)((ws_size - OFF_WEB) / SLOT_SZ);
    if (nslot > 32) nslot = 32;
  } else {
    wbf = false;
    while (chunkT > 2 &&
           OFF_WEB + (size_t)2 * chunkT * 64 * 4096 * 2 > ws_size)
      chunkT >>= 1;
  }
  const size_t OFF_ZX = OFF_WEB + (wbf ? WEB_SZ : 0);

  unsigned short* wihb  = (unsigned short*)(ws + OFF_WIH);
  unsigned short* whhb  = (unsigned short*)(ws + OFF_WHH);
  unsigned short* hr    = (unsigned short*)(ws + OFF_HR);
  float* finalb         = (float*)(ws + OFF_FIN);
  int* tsel             = (int*)(ws + OFF_TS);
  int* padsel           = (int*)(ws + OFF_PS);
  unsigned* bar         = (unsigned*)(ws + OFF_BAR);
  unsigned short* wembb = wbf ? (unsigned short*)(ws + OFF_WEB) : (unsigned short*)nullptr;
  unsigned short* zxr   = (unsigned short*)(ws + OFF_ZX);

  hipMemsetAsync(ws + OFF_BAR, 0, 40960, stream);
  k_conv<<<2048, 256, 0, stream>>>(Wih, Whh, Wemb, wihb, whhb, wembb);
  k_tsel<<<1, 512, 0, stream>>>(x, tsel, padsel);
  k_main<<<256, 256, 0, stream>>>(x, Wemb, bih, bhh, wihb, whhb, wembb, hr, finalb,
                                  tsel, padsel, zxr, bar, chunkT, nslot);
  k_logits<<<1, 256, 0, stream>>>(finalb, Wout, bout, out);
}